// Round 12
// baseline (289.373 us; speedup 1.0000x reference)
//
#include <hip/hip_runtime.h>
#include <hip/hip_bf16.h>
#include <math.h>

// ---------------- workspace layout (float offsets) ----------------
#define WS_W2H   0          // 64*160 f16 = 5120 floats   w2h[co*160 + (tap*32+ci)]
#define WS_W2L   5120       // residual plane
#define WS_W3H   10240      // 128*200 f16 = 12800 floats w3h[co*200 + (tap*64+ci)]
#define WS_W3L   23040      // -> 35840
#define WS_A1    35840      // 32
#define WS_C1    35872      // 32
#define WS_A2    35904      // 64
#define WS_C2    35968      // 64
#define WS_A3    36032      // 128
#define WS_C3    36160      // 128 -> 36288
// wl1 params: t,w fp16 f16x4-interleaved; is fp32 f32x4-interleaved. group gi=i>>2, lane o.
#define WS_T1H   36288      // -> 101824
#define WS_WW1H  101824     // -> 167360
#define WS_IS1T  167360     // -> 298432
// wl2/wl3 params fp32 float4-interleaved
#define WS_T2T   298432
#define WS_IS2T  302528
#define WS_WW2T  306624
#define WS_T3T   310720
#define WS_IS3T  314816
#define WS_WW3T  318912     // -> 323008
#define WS_FEAT  323008     // 1024*2048 floats -> end 2420160

typedef _Float16 f16x8 __attribute__((ext_vector_type(8)));
typedef _Float16 f16x4v __attribute__((ext_vector_type(4)));
typedef float    f32x4 __attribute__((ext_vector_type(4)));

struct InPtrs { const float* p[34]; };

// Branchless A&S 7.1.26 erf-based gelu: |erf err| <= 1.5e-7, ~16 VALU ops.
__device__ __forceinline__ float gelu_fast(float x) {
    float z  = 0.70710678118654752f * x;
    float az = fabsf(z);
    float t  = __builtin_amdgcn_rcpf(fmaf(0.3275911f, az, 1.0f));
    float p  = fmaf(1.061405429f, t, -1.453152027f);
    p = fmaf(p, t, 1.421413741f);
    p = fmaf(p, t, -0.284496736f);
    p = fmaf(p, t, 0.254829592f);
    p = p * t;
    float e  = __expf(-z * z);
    float erf_abs = fmaf(-p, e, 1.0f);
    float erfv = copysignf(erf_abs, z);
    return 0.5f * x * (1.0f + erfv);
}

// ---------------- prep: pack/transpose/split params ----------------
__global__ __launch_bounds__(256) void prep_kernel(InPtrs in, float* __restrict__ ws) {
    int idx = blockIdx.x * 256 + threadIdx.x;
    if (idx >= 453856) return;
    if (idx < 10240) {                       // w2 split hi/lo fp16 [co][tap*32+ci], stride 160
        int co = idx / 160; int kk = idx - co * 160;
        int tap = kk >> 5, ci = kk & 31;
        float val = in.p[7][co * 160 + ci * 5 + tap];
        _Float16 hi = (_Float16)val;
        ((_Float16*)(ws + WS_W2H))[co * 160 + kk] = hi;
        ((_Float16*)(ws + WS_W2L))[co * 160 + kk] = (_Float16)(val - (float)hi);
    } else if (idx < 35840) {                // w3 split hi/lo fp16 [co][tap*64+ci], stride 200
        int n = idx - 10240;
        int co = n / 200; int k = n - co * 200;
        float val = 0.0f;
        if (k < 192) { int ci = k & 63; int tap = k >> 6; val = in.p[13][co * 192 + ci * 3 + tap]; }
        _Float16 hi = (_Float16)val;
        ((_Float16*)(ws + WS_W3H))[co * 200 + k] = hi;
        ((_Float16*)(ws + WS_W3L))[co * 200 + k] = (_Float16)(val - (float)hi);
    } else if (idx < 36064) {                // BN folds
        int n = idx - 35840;
        int ch, offA, offC; const float *cb, *g, *bb, *m, *v;
        if (n < 32)      { ch = n;      cb = in.p[2];  g = in.p[3];  bb = in.p[4];  m = in.p[5];  v = in.p[6];  offA = WS_A1; offC = WS_C1; }
        else if (n < 96) { ch = n - 32; cb = in.p[8];  g = in.p[9];  bb = in.p[10]; m = in.p[11]; v = in.p[12]; offA = WS_A2; offC = WS_C2; }
        else             { ch = n - 96; cb = in.p[14]; g = in.p[15]; bb = in.p[16]; m = in.p[17]; v = in.p[18]; offA = WS_A3; offC = WS_C3; }
        float A = g[ch] * rsqrtf(v[ch] + 1e-5f);
        ws[offA + ch] = A;
        ws[offC + ch] = (cb[ch] - m[ch]) * A + bb[ch];
    } else if (idx < 429280) {               // wl1: t,w -> fp16 packed; is -> fp32 packed
        int n = idx - 36064;
        int arr = n / 131072; int m = n - arr * 131072;
        int o = m >> 11; int i = m & 2047;
        float val = in.p[19 + arr][o * 2048 + i];
        int pidx = ((i >> 2) * 64 + o) * 4 + (i & 3);
        if (arr == 0)      ((_Float16*)(ws + WS_T1H))[pidx]  = (_Float16)val;
        else if (arr == 1) ws[WS_IS1T + pidx] = 1.0f / (val + 1e-8f);
        else               ((_Float16*)(ws + WS_WW1H))[pidx] = (_Float16)val;
    } else {                                 // wl2/wl3: fp32 packed
        int n = idx - 429280;
        int layer = n / 12288; int m = n - layer * 12288;
        int arr = m / 4096; int mm = m - arr * 4096;
        int o = mm >> 6; int i = mm & 63;
        float val = in.p[(layer == 0 ? 24 : 29) + arr][o * 64 + i];
        if (arr == 1) val = 1.0f / (val + 1e-8f);
        int base;
        if (layer == 0) base = (arr == 0) ? WS_T2T : (arr == 1) ? WS_IS2T : WS_WW2T;
        else            base = (arr == 0) ? WS_T3T : (arr == 1) ? WS_IS3T : WS_WW3T;
        ws[base + ((i >> 2) * 64 + o) * 4 + (i & 3)] = val;
    }
}

// ---------------- KCONV: half-tile, register-split stages (acc[5][2]/acc2[4][2]) ----------------
// h1/h2 in separate LDS regions (no union) so C-epilogue can interleave with the tc-halves.
__global__ __launch_bounds__(256) void kconv_kernel(const float* __restrict__ x,
                                                    const float* __restrict__ w1,
                                                    const float* __restrict__ ws,
                                                    const _Float16* __restrict__ w3h,
                                                    const _Float16* __restrict__ w3l,
                                                    float* __restrict__ feat) {
    __shared__ __align__(16) float xs[560];
    __shared__ float w1s[224];
    __shared__ float a1s[32], c1s[32], a2s[64], c2s[64];
    __shared__ __align__(16) _Float16 h1s[276 * 40];   // 22080 B
    __shared__ __align__(16) _Float16 h2s[130 * 72];   // 18720 B

    int t = threadIdx.x;
    int b = blockIdx.x >> 1, q = blockIdx.x & 1;

    // ---- stage A ----
    for (int j = t; j < 560; j += 256) {
        int gx = 512 * q - 11 + j;
        xs[j] = (gx >= 0 && gx < 1024) ? x[b * 1024 + gx] : 0.0f;
    }
    if (t < 224) w1s[t] = w1[t];
    if (t < 32) { a1s[t] = ws[WS_A1 + t]; c1s[t] = ws[WS_C1 + t]; }
    if (t < 64) { a2s[t] = ws[WS_A2 + t]; c2s[t] = ws[WS_C2 + t]; }
    if (q == 0 && t < 64) h2s[0 * 72 + t]   = (_Float16)0.f;
    if (q == 1 && t < 64) h2s[129 * 72 + t] = (_Float16)0.f;
    __syncthreads();

    // ---- stage B: conv1+bn+gelu+maxpool2 -> h1 ----
    for (int item = t; item < 32 * 69; item += 256) {
        int rq = item >> 5, ci = item & 31;
        const float4* xp = (const float4*)(xs + 8 * rq);
        float4 X0 = xp[0], X1 = xp[1], X2 = xp[2], X3 = xp[3];
        float f[16] = {X0.x, X0.y, X0.z, X0.w, X1.x, X1.y, X1.z, X1.w,
                       X2.x, X2.y, X2.z, X2.w, X3.x, X3.y, X3.z, X3.w};
        float wk0 = w1s[ci * 7],     wk1 = w1s[ci * 7 + 1], wk2 = w1s[ci * 7 + 2];
        float wk3 = w1s[ci * 7 + 3], wk4 = w1s[ci * 7 + 4], wk5 = w1s[ci * 7 + 5];
        float wk6 = w1s[ci * 7 + 6];
        float A = a1s[ci], C = c1s[ci];
        #pragma unroll
        for (int r4 = 0; r4 < 4; ++r4) {
            int r = 4 * rq + r4;
            int hp = 256 * q - 4 + r;
            float val = 0.0f;
            if ((unsigned)hp < 512u) {
                int j = 2 * r4;
                float d0 = f[j]*wk0 + f[j+1]*wk1 + f[j+2]*wk2 + f[j+3]*wk3
                         + f[j+4]*wk4 + f[j+5]*wk5 + f[j+6]*wk6;
                float d1 = f[j+1]*wk0 + f[j+2]*wk1 + f[j+3]*wk2 + f[j+4]*wk3
                         + f[j+5]*wk4 + f[j+6]*wk5 + f[j+7]*wk6;
                val = fmaxf(gelu_fast(fmaf(d0, A, C)), gelu_fast(fmaf(d1, A, C)));
            }
            if (r < 276) h1s[r * 40 + ci] = (_Float16)val;
        }
    }
    __syncthreads();

    int w = t >> 6, lane = t & 63;
    int m = lane & 15, quad = lane >> 4;

    // ---- stage C: conv2 GEMM in two tc-halves (acc[5][2] = 40 AGPR peak) ----
    const _Float16* w2h = (const _Float16*)(ws + WS_W2H);
    const _Float16* w2l = (const _Float16*)(ws + WS_W2L);

    #pragma unroll 1
    for (int tcg = 0; tcg < 2; ++tcg) {
        f32x4 acc[5][2] = {};
        #pragma unroll
        for (int s = 0; s < 5; ++s) {
            f16x8 bh[2], bl[2];
            #pragma unroll
            for (int tcl = 0; tcl < 2; ++tcl) {
                int off = (16 * (2 * tcg + tcl) + m) * 160 + 32 * s + quad * 8;
                bh[tcl] = *(const f16x8*)(w2h + off);
                bl[tcl] = *(const f16x8*)(w2l + off);
            }
            #pragma unroll
            for (int i = 0; i < 5; ++i) {
                if (i == 4 && w != 0) continue;
                int fr = (i < 4) ? (4 * i + w) : 16;
                f16x8 ah = *(const f16x8*)(&h1s[(16 * fr + m + s) * 40 + quad * 8]);
                #pragma unroll
                for (int tcl = 0; tcl < 2; ++tcl) {
                    acc[i][tcl] = __builtin_amdgcn_mfma_f32_16x16x32_f16(ah, bh[tcl], acc[i][tcl], 0, 0, 0);
                    acc[i][tcl] = __builtin_amdgcn_mfma_f32_16x16x32_f16(ah, bl[tcl], acc[i][tcl], 0, 0, 0);
                }
            }
        }
        // epilogue for these 2 tc: bn+gelu+maxpool2 -> h2s
        #pragma unroll
        for (int i = 0; i < 5; ++i) {
            if (i == 4 && w != 0) continue;
            int fr = (i < 4) ? (4 * i + w) : 16;
            #pragma unroll
            for (int tcl = 0; tcl < 2; ++tcl) {
                int co = 16 * (2 * tcg + tcl) + m;
                float A2 = a2s[co], C2 = c2s[co];
                float g0 = gelu_fast(fmaf(acc[i][tcl][0], A2, C2));
                float g1 = gelu_fast(fmaf(acc[i][tcl][1], A2, C2));
                float g2 = gelu_fast(fmaf(acc[i][tcl][2], A2, C2));
                float g3 = gelu_fast(fmaf(acc[i][tcl][3], A2, C2));
                float p0 = fmaxf(g0, g1), p1 = fmaxf(g2, g3);
                int ll0 = 8 * fr + 2 * quad;
                int lg0 = 128 * q - 1 + ll0;
                if (ll0 < 130 && (unsigned)lg0 < 256u) h2s[ll0 * 72 + co] = (_Float16)p0;
                int ll1 = ll0 + 1, lg1 = lg0 + 1;
                if (ll1 < 130 && (unsigned)lg1 < 256u) h2s[ll1 * 72 + co] = (_Float16)p1;
            }
        }
    }
    __syncthreads();

    // ---- stage D: conv3 GEMM in two tc-halves (acc2[4][2] = 32 AGPR peak) ----
    int wr = w >> 1, wc = w & 1;

    #pragma unroll 1
    for (int tcg = 0; tcg < 2; ++tcg) {
        f32x4 acc2[4][2] = {};
        size_t boff = (size_t)(wc * 64 + m) * 200 + quad * 8;
        #pragma unroll
        for (int s = 0; s < 6; ++s) {
            int kbase = s * 32;
            int k = kbase + quad * 8;
            int koff = k >> 6, ci = k & 63;
            f16x8 ah[4], bh[2], bl[2];
            #pragma unroll
            for (int tr = 0; tr < 4; ++tr) {
                int row = 64 * wr + 16 * tr + m;
                ah[tr] = *(const f16x8*)(&h2s[(row + koff) * 72 + ci]);
            }
            #pragma unroll
            for (int tcl = 0; tcl < 2; ++tcl) {
                int tc = 2 * tcg + tcl;
                bh[tcl] = *(const f16x8*)(w3h + boff + 16 * tc * 200 + kbase);
                bl[tcl] = *(const f16x8*)(w3l + boff + 16 * tc * 200 + kbase);
            }
            #pragma unroll
            for (int tr = 0; tr < 4; ++tr)
                #pragma unroll
                for (int tcl = 0; tcl < 2; ++tcl) {
                    acc2[tr][tcl] = __builtin_amdgcn_mfma_f32_16x16x32_f16(ah[tr], bh[tcl], acc2[tr][tcl], 0, 0, 0);
                    acc2[tr][tcl] = __builtin_amdgcn_mfma_f32_16x16x32_f16(ah[tr], bl[tcl], acc2[tr][tcl], 0, 0, 0);
                }
        }
        // epilogue for these 2 tc: bn + gelu + avgpool16 -> feat
        #pragma unroll
        for (int tcl = 0; tcl < 2; ++tcl) {
            int co = 64 * wc + 16 * (2 * tcg + tcl) + m;
            float A3 = ws[WS_A3 + co], C3 = ws[WS_C3 + co];
            #pragma unroll
            for (int tr = 0; tr < 4; ++tr) {
                float s = 0.0f;
                #pragma unroll
                for (int r = 0; r < 4; ++r)
                    s += gelu_fast(fmaf(acc2[tr][tcl][r], A3, C3));
                s += __shfl_xor(s, 16, 64);
                s += __shfl_xor(s, 32, 64);
                if (quad == 0) {
                    int bin = 8 * q + 4 * wr + tr;
                    feat[(size_t)b * 2048 + co * 16 + bin] = s * 0.0625f;
                }
            }
        }
    }
}

// ---------------- K4: wavelet-KAN head (unchanged from r11) ----------------
__device__ __forceinline__ float wave_sum(float v) {
    #pragma unroll
    for (int off = 32; off > 0; off >>= 1) v += __shfl_xor(v, off, 64);
    return v;
}
__device__ __forceinline__ float silu_f(float v) {
    return v / (1.0f + __expf(-v));
}
__device__ __forceinline__ float mexh(float x, float tv, float sv, float wv) {
    float z = (x - tv) * sv, z2 = z * z;
    return (1.0f - z2) * __expf(-0.5f * z2) * wv;
}

__global__ __launch_bounds__(1024) void k4_kernel(const float* __restrict__ ws,
        const float* __restrict__ ln1g, const float* __restrict__ ln1b,
        const float* __restrict__ ln2g, const float* __restrict__ ln2b,
        const float* __restrict__ ln3g, const float* __restrict__ ln3b,
        float* __restrict__ out) {
    __shared__ __align__(16) float fs[4 * 2048];
    __shared__ float red[16 * 256];

    int t = threadIdx.x;
    int b0 = blockIdx.x * 4;
    int o = t & 63, grp = t >> 6;
    const float* feat = ws + WS_FEAT;
    const f16x4v* t1p  = (const f16x4v*)(ws + WS_T1H);
    const f16x4v* w1p  = (const f16x4v*)(ws + WS_WW1H);
    const f32x4*  is1p = (const f32x4*)(ws + WS_IS1T);

    int g0 = grp * 32;
    f16x4v tv = t1p[g0 * 64 + o];
    f16x4v wv = w1p[g0 * 64 + o];
    f32x4  sv = is1p[g0 * 64 + o];

    {
        const float4* src = (const float4*)(feat + (size_t)b0 * 2048);
        float4* dst = (float4*)fs;
        for (int i = t; i < 2048; i += 1024) dst[i] = src[i];
    }
    __syncthreads();

    float acc0 = 0.0f, acc1 = 0.0f, acc2 = 0.0f, acc3 = 0.0f;
    for (int k = 0; k < 32; ++k) {
        int gi = g0 + k;
        f16x4v tn = t1p[(gi + 1) * 64 + o];
        f16x4v wn = w1p[(gi + 1) * 64 + o];
        f32x4  sn = is1p[(gi + 1) * 64 + o];
        f32x4 f0 = *(const f32x4*)(&fs[4 * gi]);
        f32x4 f1 = *(const f32x4*)(&fs[2048 + 4 * gi]);
        f32x4 f2 = *(const f32x4*)(&fs[4096 + 4 * gi]);
        f32x4 f3 = *(const f32x4*)(&fs[6144 + 4 * gi]);
        #pragma unroll
        for (int j = 0; j < 4; ++j) {
            float tj = (float)tv[j], wj = (float)wv[j], sj = sv[j];
            acc0 += mexh(f0[j], tj, sj, wj);
            acc1 += mexh(f1[j], tj, sj, wj);
            acc2 += mexh(f2[j], tj, sj, wj);
            acc3 += mexh(f3[j], tj, sj, wj);
        }
        tv = tn; sv = sn; wv = wn;
    }
    red[grp * 256 + 0 * 64 + o] = acc0;
    red[grp * 256 + 1 * 64 + o] = acc1;
    red[grp * 256 + 2 * 64 + o] = acc2;
    red[grp * 256 + 3 * 64 + o] = acc3;
    __syncthreads();

    if (grp < 4) {
        int w = grp;
        float y = 0.0f;
        #pragma unroll
        for (int j = 0; j < 16; ++j) y += red[j * 256 + w * 64 + o];

        y = silu_f(y);
        float m = wave_sum(y) * 0.015625f;
        float d = y - m;
        float var = wave_sum(d * d) * 0.015625f;
        float yn = d * rsqrtf(var + 1e-5f) * ln1g[o] + ln1b[o];

        {
            const f32x4* t2p  = (const f32x4*)(ws + WS_T2T);
            const f32x4* is2p = (const f32x4*)(ws + WS_IS2T);
            const f32x4* w2p  = (const f32x4*)(ws + WS_WW2T);
            f32x4 tc = t2p[o], sc = is2p[o], wc = w2p[o];
            float a = 0.0f;
            for (int g = 0; g < 16; ++g) {
                f32x4 tn = t2p[(g + 1) * 64 + o];
                f32x4 sn = is2p[(g + 1) * 64 + o];
                f32x4 wn = w2p[(g + 1) * 64 + o];
                #pragma unroll
                for (int j = 0; j < 4; ++j)
                    a += mexh(__shfl(yn, 4 * g + j, 64), tc[j], sc[j], wc[j]);
                tc = tn; sc = sn; wc = wn;
            }
            float y2 = silu_f(a);
            float m2 = wave_sum(y2) * 0.015625f;
            float d2 = y2 - m2;
            float v2 = wave_sum(d2 * d2) * 0.015625f;
            yn = d2 * rsqrtf(v2 + 1e-5f) * ln2g[o] + ln2b[o];
        }
        {
            const f32x4* t3p  = (const f32x4*)(ws + WS_T3T);
            const f32x4* is3p = (const f32x4*)(ws + WS_IS3T);
            const f32x4* w3p  = (const f32x4*)(ws + WS_WW3T);
            f32x4 tc = t3p[o], sc = is3p[o], wc = w3p[o];
            float a = 0.0f;
            for (int g = 0; g < 16; ++g) {
                f32x4 tn = t3p[(g + 1) * 64 + o];
                f32x4 sn = is3p[(g + 1) * 64 + o];
                f32x4 wn = w3p[(g + 1) * 64 + o];
                #pragma unroll
                for (int j = 0; j < 4; ++j)
                    a += mexh(__shfl(yn, 4 * g + j, 64), tc[j], sc[j], wc[j]);
                tc = tn; sc = sn; wc = wn;
            }
            float y3 = silu_f(a);
            float m3 = wave_sum(y3) * 0.015625f;
            float d3 = y3 - m3;
            float v3 = wave_sum(d3 * d3) * 0.015625f;
            yn = d3 * rsqrtf(v3 + 1e-5f) * ln3g[o] + ln3b[o];
        }
        out[((size_t)b0 + w) * 64 + o] = yn;
    }
}

// ---------------- launch ----------------
extern "C" void kernel_launch(void* const* d_in, const int* in_sizes, int n_in,
                              void* d_out, int out_size, void* d_ws, size_t ws_size,
                              hipStream_t stream) {
    float* ws = (float*)d_ws;
    InPtrs ip;
    for (int i = 0; i < 34; ++i) ip.p[i] = (const float*)d_in[i];

    prep_kernel<<<1774, 256, 0, stream>>>(ip, ws);
    kconv_kernel<<<2048, 256, 0, stream>>>((const float*)d_in[0], (const float*)d_in[1],
                                           ws,
                                           (const _Float16*)(ws + WS_W3H),
                                           (const _Float16*)(ws + WS_W3L),
                                           ws + WS_FEAT);
    k4_kernel<<<256, 1024, 0, stream>>>(ws,
        (const float*)d_in[22], (const float*)d_in[23],
        (const float*)d_in[27], (const float*)d_in[28],
        (const float*)d_in[32], (const float*)d_in[33],
        (float*)d_out);
}

// Round 13
// 280.583 us; speedup vs baseline: 1.0313x; 1.0313x over previous
//
#include <hip/hip_runtime.h>
#include <hip/hip_bf16.h>
#include <math.h>

// ---------------- workspace layout (float offsets) ----------------
#define WS_W2H   0          // 64*160 f16 = 5120 floats   w2h[co*160 + (tap*32+ci)]
#define WS_W2L   5120       // residual plane
#define WS_W3H   10240      // 128*200 f16 = 12800 floats w3h[co*200 + (tap*64+ci)]
#define WS_W3L   23040      // -> 35840
#define WS_A1    35840      // 32
#define WS_C1    35872      // 32
#define WS_A2    35904      // 64
#define WS_C2    35968      // 64
#define WS_A3    36032      // 128
#define WS_C3    36160      // 128 -> 36288
// wl1 params: t,w fp16 f16x4-interleaved; is fp32 f32x4-interleaved. group gi=i>>2, lane o.
#define WS_T1H   36288      // -> 101824
#define WS_WW1H  101824     // -> 167360
#define WS_IS1T  167360     // -> 298432
// wl2/wl3 params fp32 float4-interleaved
#define WS_T2T   298432
#define WS_IS2T  302528
#define WS_WW2T  306624
#define WS_T3T   310720
#define WS_IS3T  314816
#define WS_WW3T  318912     // -> 323008
#define WS_FEAT  323008     // 1024*2048 floats -> end 2420160

typedef _Float16 f16x8 __attribute__((ext_vector_type(8)));
typedef _Float16 f16x4v __attribute__((ext_vector_type(4)));
typedef float    f32x4 __attribute__((ext_vector_type(4)));

struct InPtrs { const float* p[34]; };

// Exp-free gelu via A&S 7.1.28 erf: |erf err| <= 3e-7. 6 fma + 4 mul + 1 rcp, no v_exp.
__device__ __forceinline__ float gelu_fast(float x) {
    float az = fabsf(x) * 0.70710678118654752f;
    float t = fmaf(az, 0.0000430638f, 0.0002765672f);
    t = fmaf(t, az, 0.0001520143f);
    t = fmaf(t, az, 0.0092705272f);
    t = fmaf(t, az, 0.0422820123f);
    t = fmaf(t, az, 0.0705230784f);
    t = fmaf(t, az, 1.0f);
    float t2 = t * t;
    float t4 = t2 * t2;
    float t8 = t4 * t4;
    float t16 = t8 * t8;                       // az large -> inf -> rcp 0 -> erf 1 (correct)
    float r = __builtin_amdgcn_rcpf(t16);
    float erf_abs = 1.0f - r;
    float erfv = copysignf(erf_abs, x);
    return 0.5f * x * (1.0f + erfv);
}

// ---------------- prep: pack/transpose/split params ----------------
__global__ __launch_bounds__(256) void prep_kernel(InPtrs in, float* __restrict__ ws) {
    int idx = blockIdx.x * 256 + threadIdx.x;
    if (idx >= 453856) return;
    if (idx < 10240) {                       // w2 split hi/lo fp16 [co][tap*32+ci], stride 160
        int co = idx / 160; int kk = idx - co * 160;
        int tap = kk >> 5, ci = kk & 31;
        float val = in.p[7][co * 160 + ci * 5 + tap];
        _Float16 hi = (_Float16)val;
        ((_Float16*)(ws + WS_W2H))[co * 160 + kk] = hi;
        ((_Float16*)(ws + WS_W2L))[co * 160 + kk] = (_Float16)(val - (float)hi);
    } else if (idx < 35840) {                // w3 split hi/lo fp16 [co][tap*64+ci], stride 200
        int n = idx - 10240;
        int co = n / 200; int k = n - co * 200;
        float val = 0.0f;
        if (k < 192) { int ci = k & 63; int tap = k >> 6; val = in.p[13][co * 192 + ci * 3 + tap]; }
        _Float16 hi = (_Float16)val;
        ((_Float16*)(ws + WS_W3H))[co * 200 + k] = hi;
        ((_Float16*)(ws + WS_W3L))[co * 200 + k] = (_Float16)(val - (float)hi);
    } else if (idx < 36064) {                // BN folds
        int n = idx - 35840;
        int ch, offA, offC; const float *cb, *g, *bb, *m, *v;
        if (n < 32)      { ch = n;      cb = in.p[2];  g = in.p[3];  bb = in.p[4];  m = in.p[5];  v = in.p[6];  offA = WS_A1; offC = WS_C1; }
        else if (n < 96) { ch = n - 32; cb = in.p[8];  g = in.p[9];  bb = in.p[10]; m = in.p[11]; v = in.p[12]; offA = WS_A2; offC = WS_C2; }
        else             { ch = n - 96; cb = in.p[14]; g = in.p[15]; bb = in.p[16]; m = in.p[17]; v = in.p[18]; offA = WS_A3; offC = WS_C3; }
        float A = g[ch] * rsqrtf(v[ch] + 1e-5f);
        ws[offA + ch] = A;
        ws[offC + ch] = (cb[ch] - m[ch]) * A + bb[ch];
    } else if (idx < 429280) {               // wl1: t,w -> fp16 packed; is -> fp32 packed
        int n = idx - 36064;
        int arr = n / 131072; int m = n - arr * 131072;
        int o = m >> 11; int i = m & 2047;
        float val = in.p[19 + arr][o * 2048 + i];
        int pidx = ((i >> 2) * 64 + o) * 4 + (i & 3);
        if (arr == 0)      ((_Float16*)(ws + WS_T1H))[pidx]  = (_Float16)val;
        else if (arr == 1) ws[WS_IS1T + pidx] = 1.0f / (val + 1e-8f);
        else               ((_Float16*)(ws + WS_WW1H))[pidx] = (_Float16)val;
    } else {                                 // wl2/wl3: fp32 packed
        int n = idx - 429280;
        int layer = n / 12288; int m = n - layer * 12288;
        int arr = m / 4096; int mm = m - arr * 4096;
        int o = mm >> 6; int i = mm & 63;
        float val = in.p[(layer == 0 ? 24 : 29) + arr][o * 64 + i];
        if (arr == 1) val = 1.0f / (val + 1e-8f);
        int base;
        if (layer == 0) base = (arr == 0) ? WS_T2T : (arr == 1) ? WS_IS2T : WS_WW2T;
        else            base = (arr == 0) ? WS_T3T : (arr == 1) ? WS_IS3T : WS_WW3T;
        ws[base + ((i >> 2) * 64 + o) * 4 + (i & 3)] = val;
    }
}

// ---------------- KCONV (r11 monolithic, best-known): conv1 -> conv2 MFMA -> h2 LDS -> conv3 MFMA -> feat ----------------
__global__ __launch_bounds__(256) void kconv_kernel(const float* __restrict__ x,
                                                    const float* __restrict__ w1,
                                                    const float* __restrict__ ws,
                                                    const _Float16* __restrict__ w3h,
                                                    const _Float16* __restrict__ w3l,
                                                    float* __restrict__ feat) {
    __shared__ __align__(16) float xs[560];
    __shared__ float w1s[224];
    __shared__ float a1s[32], c1s[32], a2s[64], c2s[64];
    __shared__ __align__(16) _Float16 U[276 * 40];   // 22080 B union (h1 / h2)

    _Float16* h1s = U;

    int t = threadIdx.x;
    int b = blockIdx.x >> 1, q = blockIdx.x & 1;

    for (int j = t; j < 560; j += 256) {
        int gx = 512 * q - 11 + j;
        xs[j] = (gx >= 0 && gx < 1024) ? x[b * 1024 + gx] : 0.0f;
    }
    if (t < 224) w1s[t] = w1[t];
    if (t < 32) { a1s[t] = ws[WS_A1 + t]; c1s[t] = ws[WS_C1 + t]; }
    if (t < 64) { a2s[t] = ws[WS_A2 + t]; c2s[t] = ws[WS_C2 + t]; }
    __syncthreads();

    for (int item = t; item < 32 * 69; item += 256) {
        int rq = item >> 5, ci = item & 31;
        const float4* xp = (const float4*)(xs + 8 * rq);
        float4 X0 = xp[0], X1 = xp[1], X2 = xp[2], X3 = xp[3];
        float f[16] = {X0.x, X0.y, X0.z, X0.w, X1.x, X1.y, X1.z, X1.w,
                       X2.x, X2.y, X2.z, X2.w, X3.x, X3.y, X3.z, X3.w};
        float wk0 = w1s[ci * 7],     wk1 = w1s[ci * 7 + 1], wk2 = w1s[ci * 7 + 2];
        float wk3 = w1s[ci * 7 + 3], wk4 = w1s[ci * 7 + 4], wk5 = w1s[ci * 7 + 5];
        float wk6 = w1s[ci * 7 + 6];
        float A = a1s[ci], C = c1s[ci];
        #pragma unroll
        for (int r4 = 0; r4 < 4; ++r4) {
            int r = 4 * rq + r4;
            int hp = 256 * q - 4 + r;
            float val = 0.0f;
            if ((unsigned)hp < 512u) {
                int j = 2 * r4;
                float d0 = f[j]*wk0 + f[j+1]*wk1 + f[j+2]*wk2 + f[j+3]*wk3
                         + f[j+4]*wk4 + f[j+5]*wk5 + f[j+6]*wk6;
                float d1 = f[j+1]*wk0 + f[j+2]*wk1 + f[j+3]*wk2 + f[j+4]*wk3
                         + f[j+5]*wk4 + f[j+6]*wk5 + f[j+7]*wk6;
                val = fmaxf(gelu_fast(fmaf(d0, A, C)), gelu_fast(fmaf(d1, A, C)));
            }
            if (r < 276) h1s[r * 40 + ci] = (_Float16)val;
        }
    }
    __syncthreads();

    int w = t >> 6, lane = t & 63;
    int m = lane & 15, quad = lane >> 4;

    const _Float16* w2h = (const _Float16*)(ws + WS_W2H);
    const _Float16* w2l = (const _Float16*)(ws + WS_W2L);
    f32x4 acc[5][4] = {};

    #pragma unroll
    for (int s = 0; s < 5; ++s) {
        f16x8 bh[4], bl[4];
        #pragma unroll
        for (int tc = 0; tc < 4; ++tc) {
            int off = (16 * tc + m) * 160 + 32 * s + quad * 8;
            bh[tc] = *(const f16x8*)(w2h + off);
            bl[tc] = *(const f16x8*)(w2l + off);
        }
        #pragma unroll
        for (int i = 0; i < 5; ++i) {
            if (i == 4 && w != 0) continue;
            int fr = (i < 4) ? (4 * i + w) : 16;
            f16x8 ah = *(const f16x8*)(&h1s[(16 * fr + m + s) * 40 + quad * 8]);
            #pragma unroll
            for (int tc = 0; tc < 4; ++tc) {
                acc[i][tc] = __builtin_amdgcn_mfma_f32_16x16x32_f16(ah, bh[tc], acc[i][tc], 0, 0, 0);
                acc[i][tc] = __builtin_amdgcn_mfma_f32_16x16x32_f16(ah, bl[tc], acc[i][tc], 0, 0, 0);
            }
        }
    }
    __syncthreads();

    _Float16* h2s = U;   // 130 rows x 72 halves
    if (q == 0 && t < 64) h2s[0 * 72 + t]   = (_Float16)0.f;
    if (q == 1 && t < 64) h2s[129 * 72 + t] = (_Float16)0.f;

    #pragma unroll
    for (int i = 0; i < 5; ++i) {
        if (i == 4 && w != 0) continue;
        int fr = (i < 4) ? (4 * i + w) : 16;
        #pragma unroll
        for (int tc = 0; tc < 4; ++tc) {
            int co = 16 * tc + m;
            float A2 = a2s[co], C2 = c2s[co];
            float g0 = gelu_fast(fmaf(acc[i][tc][0], A2, C2));
            float g1 = gelu_fast(fmaf(acc[i][tc][1], A2, C2));
            float g2 = gelu_fast(fmaf(acc[i][tc][2], A2, C2));
            float g3 = gelu_fast(fmaf(acc[i][tc][3], A2, C2));
            float p0 = fmaxf(g0, g1), p1 = fmaxf(g2, g3);
            int ll0 = 8 * fr + 2 * quad;
            int lg0 = 128 * q - 1 + ll0;
            if (ll0 < 130 && (unsigned)lg0 < 256u) h2s[ll0 * 72 + co] = (_Float16)p0;
            int ll1 = ll0 + 1, lg1 = lg0 + 1;
            if (ll1 < 130 && (unsigned)lg1 < 256u) h2s[ll1 * 72 + co] = (_Float16)p1;
        }
    }
    __syncthreads();

    int wr = w >> 1, wc = w & 1;
    f32x4 acc2[4][4] = {};
    size_t boff = (size_t)(wc * 64 + m) * 200 + quad * 8;

    #pragma unroll
    for (int s = 0; s < 6; ++s) {
        int kbase = s * 32;
        int k = kbase + quad * 8;
        int koff = k >> 6, ci = k & 63;
        f16x8 ah[4], bh[4], bl[4];
        #pragma unroll
        for (int tr = 0; tr < 4; ++tr) {
            int row = 64 * wr + 16 * tr + m;
            ah[tr] = *(const f16x8*)(&h2s[(row + koff) * 72 + ci]);
        }
        #pragma unroll
        for (int tc = 0; tc < 4; ++tc) {
            bh[tc] = *(const f16x8*)(w3h + boff + 16 * tc * 200 + kbase);
            bl[tc] = *(const f16x8*)(w3l + boff + 16 * tc * 200 + kbase);
        }
        #pragma unroll
        for (int tr = 0; tr < 4; ++tr)
            #pragma unroll
            for (int tc = 0; tc < 4; ++tc) {
                acc2[tr][tc] = __builtin_amdgcn_mfma_f32_16x16x32_f16(ah[tr], bh[tc], acc2[tr][tc], 0, 0, 0);
                acc2[tr][tc] = __builtin_amdgcn_mfma_f32_16x16x32_f16(ah[tr], bl[tc], acc2[tr][tc], 0, 0, 0);
            }
    }

    #pragma unroll
    for (int tc = 0; tc < 4; ++tc) {
        int co = 64 * wc + 16 * tc + m;
        float A3 = ws[WS_A3 + co], C3 = ws[WS_C3 + co];
        #pragma unroll
        for (int tr = 0; tr < 4; ++tr) {
            float s = 0.0f;
            #pragma unroll
            for (int r = 0; r < 4; ++r)
                s += gelu_fast(fmaf(acc2[tr][tc][r], A3, C3));
            s += __shfl_xor(s, 16, 64);
            s += __shfl_xor(s, 32, 64);
            if (quad == 0) {
                int bin = 8 * q + 4 * wr + tr;
                feat[(size_t)b * 2048 + co * 16 + bin] = s * 0.0625f;
            }
        }
    }
}

// ---------------- K4: wavelet-KAN head (r11-exact) ----------------
__device__ __forceinline__ float wave_sum(float v) {
    #pragma unroll
    for (int off = 32; off > 0; off >>= 1) v += __shfl_xor(v, off, 64);
    return v;
}
__device__ __forceinline__ float silu_f(float v) {
    return v / (1.0f + __expf(-v));
}
__device__ __forceinline__ float mexh(float x, float tv, float sv, float wv) {
    float z = (x - tv) * sv, z2 = z * z;
    return (1.0f - z2) * __expf(-0.5f * z2) * wv;
}

__global__ __launch_bounds__(1024) void k4_kernel(const float* __restrict__ ws,
        const float* __restrict__ ln1g, const float* __restrict__ ln1b,
        const float* __restrict__ ln2g, const float* __restrict__ ln2b,
        const float* __restrict__ ln3g, const float* __restrict__ ln3b,
        float* __restrict__ out) {
    __shared__ __align__(16) float fs[4 * 2048];
    __shared__ float red[16 * 256];

    int t = threadIdx.x;
    int b0 = blockIdx.x * 4;
    int o = t & 63, grp = t >> 6;
    const float* feat = ws + WS_FEAT;
    const f16x4v* t1p  = (const f16x4v*)(ws + WS_T1H);
    const f16x4v* w1p  = (const f16x4v*)(ws + WS_WW1H);
    const f32x4*  is1p = (const f32x4*)(ws + WS_IS1T);

    int g0 = grp * 32;
    f16x4v tv = t1p[g0 * 64 + o];
    f16x4v wv = w1p[g0 * 64 + o];
    f32x4  sv = is1p[g0 * 64 + o];

    {
        const float4* src = (const float4*)(feat + (size_t)b0 * 2048);
        float4* dst = (float4*)fs;
        for (int i = t; i < 2048; i += 1024) dst[i] = src[i];
    }
    __syncthreads();

    float acc0 = 0.0f, acc1 = 0.0f, acc2 = 0.0f, acc3 = 0.0f;
    for (int k = 0; k < 32; ++k) {
        int gi = g0 + k;
        f16x4v tn = t1p[(gi + 1) * 64 + o];
        f16x4v wn = w1p[(gi + 1) * 64 + o];
        f32x4  sn = is1p[(gi + 1) * 64 + o];
        f32x4 f0 = *(const f32x4*)(&fs[4 * gi]);
        f32x4 f1 = *(const f32x4*)(&fs[2048 + 4 * gi]);
        f32x4 f2 = *(const f32x4*)(&fs[4096 + 4 * gi]);
        f32x4 f3 = *(const f32x4*)(&fs[6144 + 4 * gi]);
        #pragma unroll
        for (int j = 0; j < 4; ++j) {
            float tj = (float)tv[j], wj = (float)wv[j], sj = sv[j];
            acc0 += mexh(f0[j], tj, sj, wj);
            acc1 += mexh(f1[j], tj, sj, wj);
            acc2 += mexh(f2[j], tj, sj, wj);
            acc3 += mexh(f3[j], tj, sj, wj);
        }
        tv = tn; sv = sn; wv = wn;
    }
    red[grp * 256 + 0 * 64 + o] = acc0;
    red[grp * 256 + 1 * 64 + o] = acc1;
    red[grp * 256 + 2 * 64 + o] = acc2;
    red[grp * 256 + 3 * 64 + o] = acc3;
    __syncthreads();

    if (grp < 4) {
        int w = grp;
        float y = 0.0f;
        #pragma unroll
        for (int j = 0; j < 16; ++j) y += red[j * 256 + w * 64 + o];

        y = silu_f(y);
        float m = wave_sum(y) * 0.015625f;
        float d = y - m;
        float var = wave_sum(d * d) * 0.015625f;
        float yn = d * rsqrtf(var + 1e-5f) * ln1g[o] + ln1b[o];

        {
            const f32x4* t2p  = (const f32x4*)(ws + WS_T2T);
            const f32x4* is2p = (const f32x4*)(ws + WS_IS2T);
            const f32x4* w2p  = (const f32x4*)(ws + WS_WW2T);
            f32x4 tc = t2p[o], sc = is2p[o], wc = w2p[o];
            float a = 0.0f;
            for (int g = 0; g < 16; ++g) {
                f32x4 tn = t2p[(g + 1) * 64 + o];
                f32x4 sn = is2p[(g + 1) * 64 + o];
                f32x4 wn = w2p[(g + 1) * 64 + o];
                #pragma unroll
                for (int j = 0; j < 4; ++j)
                    a += mexh(__shfl(yn, 4 * g + j, 64), tc[j], sc[j], wc[j]);
                tc = tn; sc = sn; wc = wn;
            }
            float y2 = silu_f(a);
            float m2 = wave_sum(y2) * 0.015625f;
            float d2 = y2 - m2;
            float v2 = wave_sum(d2 * d2) * 0.015625f;
            yn = d2 * rsqrtf(v2 + 1e-5f) * ln2g[o] + ln2b[o];
        }
        {
            const f32x4* t3p  = (const f32x4*)(ws + WS_T3T);
            const f32x4* is3p = (const f32x4*)(ws + WS_IS3T);
            const f32x4* w3p  = (const f32x4*)(ws + WS_WW3T);
            f32x4 tc = t3p[o], sc = is3p[o], wc = w3p[o];
            float a = 0.0f;
            for (int g = 0; g < 16; ++g) {
                f32x4 tn = t3p[(g + 1) * 64 + o];
                f32x4 sn = is3p[(g + 1) * 64 + o];
                f32x4 wn = w3p[(g + 1) * 64 + o];
                #pragma unroll
                for (int j = 0; j < 4; ++j)
                    a += mexh(__shfl(yn, 4 * g + j, 64), tc[j], sc[j], wc[j]);
                tc = tn; sc = sn; wc = wn;
            }
            float y3 = silu_f(a);
            float m3 = wave_sum(y3) * 0.015625f;
            float d3 = y3 - m3;
            float v3 = wave_sum(d3 * d3) * 0.015625f;
            yn = d3 * rsqrtf(v3 + 1e-5f) * ln3g[o] + ln3b[o];
        }
        out[((size_t)b0 + w) * 64 + o] = yn;
    }
}

// ---------------- launch ----------------
extern "C" void kernel_launch(void* const* d_in, const int* in_sizes, int n_in,
                              void* d_out, int out_size, void* d_ws, size_t ws_size,
                              hipStream_t stream) {
    float* ws = (float*)d_ws;
    InPtrs ip;
    for (int i = 0; i < 34; ++i) ip.p[i] = (const float*)d_in[i];

    prep_kernel<<<1774, 256, 0, stream>>>(ip, ws);
    kconv_kernel<<<2048, 256, 0, stream>>>((const float*)d_in[0], (const float*)d_in[1],
                                           ws,
                                           (const _Float16*)(ws + WS_W3H),
                                           (const _Float16*)(ws + WS_W3L),
                                           ws + WS_FEAT);
    k4_kernel<<<256, 1024, 0, stream>>>(ws,
        (const float*)d_in[22], (const float*)d_in[23],
        (const float*)d_in[27], (const float*)d_in[28],
        (const float*)d_in[32], (const float*)d_in[33],
        (float*)d_out);
}